// Round 5
// baseline (760.305 us; speedup 1.0000x reference)
//
#include <hip/hip_runtime.h>
#include <hip/hip_bf16.h>

typedef _Float16 h16;
typedef _Float16 f16x8 __attribute__((ext_vector_type(8)));
typedef float f32x4 __attribute__((ext_vector_type(4)));

constexpr int T = 8192, H = 1024, F = 2816, E = 8;
constexpr int NENT = T * 2;
constexpr int SLACK = 128;
constexpr int BM = 256, BK = 64;
constexpr int MT256 = T / BM;       // 32
constexpr int NT1b = F / 128;       // 22  (gemm1 BN=128)
constexpr int NT2b = H / 256;       // 4   (gemm2 BN=256)
constexpr int NKH = H / BK;         // 16
constexpr int NKF = F / BK;         // 44

#define GLD16(gptr, lptr)                                                        \
  __builtin_amdgcn_global_load_lds(                                              \
      (const __attribute__((address_space(1))) unsigned int*)(gptr),             \
      (__attribute__((address_space(3))) unsigned int*)(lptr), 16, 0, 0)

#define ASM_VMCNT(n) asm volatile("s_waitcnt vmcnt(" #n ")" ::: "memory")
#define ASM_LGKM0    asm volatile("s_waitcnt lgkmcnt(0)" ::: "memory")
#define SBAR()       __builtin_amdgcn_s_barrier()
#define SCHEDB()     __builtin_amdgcn_sched_barrier(0)

// LDS tile: rows x 64 h16 (128 B/row), XOR-swizzled k-slots.
__device__ __forceinline__ int src_col(int lane) {
  return (((lane & 7) ^ ((lane >> 3) & 7)) * 8);
}
__device__ __forceinline__ int frag_off(int row, int s) {
  return row * 128 + ((s ^ (row & 7)) * 16);
}

// ---------------- routing ----------------
__global__ void k_routing(const float* __restrict__ logits,
                          int* __restrict__ top_i, float* __restrict__ top_w,
                          int* __restrict__ counts) {
  int t = blockIdx.x * blockDim.x + threadIdx.x;
  if (t >= T) return;
  float l[E];
#pragma unroll
  for (int j = 0; j < E; ++j) l[j] = logits[t * E + j];
  int i1 = 0; float v1 = l[0];
#pragma unroll
  for (int j = 1; j < E; ++j) if (l[j] > v1) { v1 = l[j]; i1 = j; }
  int i2 = -1; float v2 = -3.4e38f;
#pragma unroll
  for (int j = 0; j < E; ++j) if (j != i1 && l[j] > v2) { v2 = l[j]; i2 = j; }
  float e2 = __expf(v2 - v1);
  float inv = 1.0f / (1.0f + e2);
  top_i[2 * t] = i1; top_i[2 * t + 1] = i2;
  top_w[2 * t] = inv; top_w[2 * t + 1] = e2 * inv;
  atomicAdd(&counts[i1], 1);
  atomicAdd(&counts[i2], 1);
}

__global__ void k_init_counts(int* counts) {
  if (threadIdx.x < E) counts[threadIdx.x] = 0;
}

__global__ void k_prefix(const int* __restrict__ counts, int* __restrict__ offs,
                         int* __restrict__ fill) {
  if (threadIdx.x == 0) {
    int s = 0;
    for (int e = 0; e < E; ++e) { offs[e] = s; s += counts[e]; fill[e] = 0; }
  }
}

__global__ void k_scatter(const int* __restrict__ top_i, const float* __restrict__ top_w,
                          const int* __restrict__ offs, int* __restrict__ fill,
                          int* __restrict__ etok, float* __restrict__ ew,
                          int* __restrict__ tok2ent) {
  int t = blockIdx.x * blockDim.x + threadIdx.x;
  if (t >= T) return;
#pragma unroll
  for (int k = 0; k < 2; ++k) {
    int e = top_i[2 * t + k];
    int pos = atomicAdd(&fill[e], 1);
    int idx = offs[e] + pos;
    etok[idx] = t;
    ew[idx] = top_w[2 * t + k];
    tok2ent[2 * t + k] = idx;
  }
}

// ---------------- fp32 -> fp16 ----------------
__global__ void k_cvt(const float* __restrict__ s, h16* __restrict__ d) {
  size_t i = (size_t)(blockIdx.x * blockDim.x + threadIdx.x) * 8;
  float4 a = *(const float4*)(s + i);
  float4 b = *(const float4*)(s + i + 4);
  f16x8 h = {(h16)a.x, (h16)a.y, (h16)a.z, (h16)a.w,
             (h16)b.x, (h16)b.y, (h16)b.z, (h16)b.w};
  *(f16x8*)(d + i) = h;
}

// ---------------- combine: out[t] = w0*y[p0] + w1*y[p1] ----------------
__global__ void k_combine(const h16* __restrict__ y, const int* __restrict__ tok2ent,
                          const float* __restrict__ topw, float* __restrict__ out) {
  int i = blockIdx.x * blockDim.x + threadIdx.x;
  int t = i >> 7;
  int h0 = (i & 127) << 3;
  int p0 = tok2ent[2 * t], p1 = tok2ent[2 * t + 1];
  float w0 = topw[2 * t], w1 = topw[2 * t + 1];
  f16x8 y0 = *(const f16x8*)(y + (size_t)p0 * H + h0);
  f16x8 y1 = *(const f16x8*)(y + (size_t)p1 * H + h0);
  float4 o0, o1;
  o0.x = w0 * (float)y0[0] + w1 * (float)y1[0];
  o0.y = w0 * (float)y0[1] + w1 * (float)y1[1];
  o0.z = w0 * (float)y0[2] + w1 * (float)y1[2];
  o0.w = w0 * (float)y0[3] + w1 * (float)y1[3];
  o1.x = w0 * (float)y0[4] + w1 * (float)y1[4];
  o1.y = w0 * (float)y0[5] + w1 * (float)y1[5];
  o1.z = w0 * (float)y0[6] + w1 * (float)y1[6];
  o1.w = w0 * (float)y0[7] + w1 * (float)y1[7];
  *(float4*)(out + (size_t)t * H + h0) = o0;
  *(float4*)(out + (size_t)t * H + h0 + 4) = o1;
}

// ---------------- GEMM1: 256x128, gate+up fused, 4-phase fine interleave ----------------
__launch_bounds__(512, 2)
__global__ void k_gemm1(const h16* __restrict__ x16,
                        const h16* __restrict__ w1h, const h16* __restrict__ w3h,
                        const int* __restrict__ counts, const int* __restrict__ offs,
                        const int* __restrict__ etok, h16* __restrict__ act) {
  constexpr int NWG = E * MT256 * NT1b;              // 5632, %8==0
  int orig = blockIdx.x;
  int bid = (orig & 7) * (NWG / 8) + (orig >> 3);    // XCD-chunked swizzle
  int e  = bid / (MT256 * NT1b);
  int r  = bid % (MT256 * NT1b);
  int nt = r / MT256;
  int mt = r % MT256;
  int n_e = counts[e];
  if (mt * BM >= n_e) return;
  int base = offs[e];

  __shared__ h16 As[2][BM * BK];      // 32 KB each
  __shared__ h16 B1s[2][128 * BK];    // 16 KB each
  __shared__ h16 B3s[2][128 * BK];    // 16 KB each

  int tid = threadIdx.x;
  int lane = tid & 63, wid = tid >> 6;
  int wm = (wid >> 2) * 128;
  int wn = (wid & 3) * 32;
  int lr = lane & 15, ls = lane >> 4;

  const h16* gA[4];
#pragma unroll
  for (int j = 0; j < 4; ++j) {
    int c = wid * 4 + j;
    int row = c * 8 + (lane >> 3);
    int gr = mt * BM + row; if (gr >= n_e) gr = n_e - 1;
    gA[j] = x16 + (size_t)etok[base + gr] * H + src_col(lane);
  }
  const h16* gB1[2]; const h16* gB3[2];
#pragma unroll
  for (int j = 0; j < 2; ++j) {
    int c = wid * 2 + j;
    int row = c * 8 + (lane >> 3);
    size_t w = ((size_t)e * F + (size_t)nt * 128 + row) * H + src_col(lane);
    gB1[j] = w1h + w;
    gB3[j] = w3h + w;
  }

  auto stageA = [&](int b, int k0) {
#pragma unroll
    for (int j = 0; j < 4; ++j)
      GLD16(gA[j] + k0, (char*)&As[b][0] + (wid * 4 + j) * 1024);
  };
  auto stageB = [&](int b, int k0) {
#pragma unroll
    for (int j = 0; j < 2; ++j) {
      GLD16(gB1[j] + k0, (char*)&B1s[b][0] + (wid * 2 + j) * 1024);
      GLD16(gB3[j] + k0, (char*)&B3s[b][0] + (wid * 2 + j) * 1024);
    }
  };

  int aoff[8][2], boff[2][2];
#pragma unroll
  for (int mi = 0; mi < 8; ++mi)
#pragma unroll
    for (int h = 0; h < 2; ++h)
      aoff[mi][h] = frag_off(wm + mi * 16 + lr, h * 4 + ls);
#pragma unroll
  for (int nj = 0; nj < 2; ++nj)
#pragma unroll
    for (int h = 0; h < 2; ++h)
      boff[nj][h] = frag_off(wn + nj * 16 + lr, h * 4 + ls);

  f32x4 ag[8][2] = {{{0.f,0.f,0.f,0.f}}};
  f32x4 au[8][2] = {{{0.f,0.f,0.f,0.f}}};

#define G1_QUAD(MB, A2)                                                         \
  __builtin_amdgcn_s_setprio(1);                                                \
  _Pragma("unroll") for (int m = 0; m < 2; ++m)                                 \
  _Pragma("unroll") for (int nj = 0; nj < 2; ++nj)                              \
  _Pragma("unroll") for (int kh = 0; kh < 2; ++kh) {                            \
    ag[MB + m][nj] = __builtin_amdgcn_mfma_f32_16x16x32_f16(A2[m][kh], B1f[nj][kh], ag[MB + m][nj], 0, 0, 0); \
    au[MB + m][nj] = __builtin_amdgcn_mfma_f32_16x16x32_f16(A2[m][kh], B3f[nj][kh], au[MB + m][nj], 0, 0, 0); \
  }                                                                             \
  __builtin_amdgcn_s_setprio(0);

  stageA(0, 0); stageB(0, 0);
  stageA(1, BK); stageB(1, BK);
  ASM_VMCNT(8);
  SBAR();

  for (int t = 0; t < NKH; ++t) {
    const char* ab  = (const char*)&As[t & 1][0];
    const char* b1b = (const char*)&B1s[t & 1][0];
    const char* b3b = (const char*)&B3s[t & 1][0];
    // ---- phase 0: read A mi0-1 + all B; MFMA mi0-1 ----
    f16x8 aq[2][2], B1f[2][2], B3f[2][2];
#pragma unroll
    for (int m = 0; m < 2; ++m)
#pragma unroll
      for (int kh = 0; kh < 2; ++kh)
        aq[m][kh] = *(const f16x8*)(ab + aoff[m][kh]);
#pragma unroll
    for (int nj = 0; nj < 2; ++nj)
#pragma unroll
      for (int kh = 0; kh < 2; ++kh) {
        B1f[nj][kh] = *(const f16x8*)(b1b + boff[nj][kh]);
        B3f[nj][kh] = *(const f16x8*)(b3b + boff[nj][kh]);
      }
    SBAR();
    G1_QUAD(0, aq)
    SBAR();
    // ---- phase 1: read A mi2-7; MFMA mi2-3 ----
    f16x8 ah[6][2];
#pragma unroll
    for (int m = 0; m < 6; ++m)
#pragma unroll
      for (int kh = 0; kh < 2; ++kh)
        ah[m][kh] = *(const f16x8*)(ab + aoff[2 + m][kh]);
    ASM_LGKM0;            // all my reads of buf[t&1] retired
    SCHEDB();
    SBAR();
    G1_QUAD(2, (&ah[0]))
    SBAR();               // every wave's reads retired -> buffer reusable
    // ---- phase 2: stage A of t+2 into buf[t&1]; MFMA mi4-5 ----
    if (t + 2 < NKH) stageA(t & 1, (t + 2) * BK);
    SBAR();
    G1_QUAD(4, (&ah[2]))
    SBAR();
    // ---- phase 3: stage B of t+2; MFMA mi6-7; counted vmcnt ----
    if (t + 2 < NKH) stageB(t & 1, (t + 2) * BK);
    SBAR();
    G1_QUAD(6, (&ah[4]))
    if (t + 2 < NKH) { ASM_VMCNT(8); } else { ASM_VMCNT(0); }
    SBAR();
  }
#undef G1_QUAD

  // epilogue: silu(g)*u -> act fp16
#pragma unroll
  for (int mi = 0; mi < 8; ++mi) {
#pragma unroll
    for (int rr = 0; rr < 4; ++rr) {
      int grow = mt * BM + wm + mi * 16 + ls * 4 + rr;
      if (grow < n_e) {
        size_t rowb = (size_t)(base + grow) * F + (size_t)nt * 128 + wn;
#pragma unroll
        for (int nj = 0; nj < 2; ++nj) {
          float g = ag[mi][nj][rr];
          float u = au[mi][nj][rr];
          float s = g / (1.0f + __expf(-g)) * u;
          act[rowb + nj * 16 + lr] = (h16)s;
        }
      }
    }
  }
}

// ---------------- GEMM2: 256x256, y = act @ w2^T, 4-phase fine interleave ----------------
__launch_bounds__(512, 2)
__global__ void k_gemm2(const h16* __restrict__ act, const h16* __restrict__ w2h,
                        const int* __restrict__ counts, const int* __restrict__ offs,
                        h16* __restrict__ y16) {
  constexpr int NWG = E * MT256 * NT2b;              // 1024, %8==0
  int orig = blockIdx.x;
  int bid = (orig & 7) * (NWG / 8) + (orig >> 3);
  int e  = bid / (MT256 * NT2b);
  int r  = bid % (MT256 * NT2b);
  int nt = r / MT256;
  int mt = r % MT256;
  int n_e = counts[e];
  if (mt * BM >= n_e) return;
  int base = offs[e];

  __shared__ h16 As[2][BM * BK];      // 32 KB each
  __shared__ h16 Bs[2][BM * BK];      // 32 KB each

  int tid = threadIdx.x;
  int lane = tid & 63, wid = tid >> 6;
  int wm = (wid >> 2) * 128;
  int wn = (wid & 3) * 64;
  int lr = lane & 15, ls = lane >> 4;

  const h16* gA[4]; const h16* gB[4];
#pragma unroll
  for (int j = 0; j < 4; ++j) {
    int c = wid * 4 + j;
    int row = c * 8 + (lane >> 3);
    int gr = mt * BM + row; if (gr >= n_e) gr = n_e - 1;
    gA[j] = act + (size_t)(base + gr) * F + src_col(lane);
    gB[j] = w2h + ((size_t)e * H + (size_t)nt * 256 + row) * F + src_col(lane);
  }

  auto stageA = [&](int b, int k0) {
#pragma unroll
    for (int j = 0; j < 4; ++j)
      GLD16(gA[j] + k0, (char*)&As[b][0] + (wid * 4 + j) * 1024);
  };
  auto stageB = [&](int b, int k0) {
#pragma unroll
    for (int j = 0; j < 4; ++j)
      GLD16(gB[j] + k0, (char*)&Bs[b][0] + (wid * 4 + j) * 1024);
  };

  int aoff[8][2], boff[4][2];
#pragma unroll
  for (int mi = 0; mi < 8; ++mi)
#pragma unroll
    for (int h = 0; h < 2; ++h)
      aoff[mi][h] = frag_off(wm + mi * 16 + lr, h * 4 + ls);
#pragma unroll
  for (int nj = 0; nj < 4; ++nj)
#pragma unroll
    for (int h = 0; h < 2; ++h)
      boff[nj][h] = frag_off(wn + nj * 16 + lr, h * 4 + ls);

  f32x4 acc[8][4] = {{{0.f,0.f,0.f,0.f}}};

#define G2_QUAD(MB, A2)                                                         \
  __builtin_amdgcn_s_setprio(1);                                                \
  _Pragma("unroll") for (int m = 0; m < 2; ++m)                                 \
  _Pragma("unroll") for (int nj = 0; nj < 4; ++nj)                              \
  _Pragma("unroll") for (int kh = 0; kh < 2; ++kh) {                            \
    acc[MB + m][nj] = __builtin_amdgcn_mfma_f32_16x16x32_f16(A2[m][kh], bf[nj][kh], acc[MB + m][nj], 0, 0, 0); \
  }                                                                             \
  __builtin_amdgcn_s_setprio(0);

  stageA(0, 0); stageB(0, 0);
  stageA(1, BK); stageB(1, BK);
  ASM_VMCNT(8);
  SBAR();

  for (int t = 0; t < NKF; ++t) {
    const char* ab = (const char*)&As[t & 1][0];
    const char* bb = (const char*)&Bs[t & 1][0];
    // ---- phase 0: read A mi0-1 + all B; MFMA mi0-1 ----
    f16x8 aq[2][2], bf[4][2];
#pragma unroll
    for (int m = 0; m < 2; ++m)
#pragma unroll
      for (int kh = 0; kh < 2; ++kh)
        aq[m][kh] = *(const f16x8*)(ab + aoff[m][kh]);
#pragma unroll
    for (int nj = 0; nj < 4; ++nj)
#pragma unroll
      for (int kh = 0; kh < 2; ++kh)
        bf[nj][kh] = *(const f16x8*)(bb + boff[nj][kh]);
    SBAR();
    G2_QUAD(0, aq)
    SBAR();
    // ---- phase 1: read A mi2-7; MFMA mi2-3 ----
    f16x8 ah[6][2];
#pragma unroll
    for (int m = 0; m < 6; ++m)
#pragma unroll
      for (int kh = 0; kh < 2; ++kh)
        ah[m][kh] = *(const f16x8*)(ab + aoff[2 + m][kh]);
    ASM_LGKM0;
    SCHEDB();
    SBAR();
    G2_QUAD(2, (&ah[0]))
    SBAR();
    // ---- phase 2: stage A of t+2; MFMA mi4-5 ----
    if (t + 2 < NKF) stageA(t & 1, (t + 2) * BK);
    SBAR();
    G2_QUAD(4, (&ah[2]))
    SBAR();
    // ---- phase 3: stage B of t+2; MFMA mi6-7; counted vmcnt ----
    if (t + 2 < NKF) stageB(t & 1, (t + 2) * BK);
    SBAR();
    G2_QUAD(6, (&ah[4]))
    if (t + 2 < NKF) { ASM_VMCNT(8); } else { ASM_VMCNT(0); }
    SBAR();
  }
#undef G2_QUAD

#pragma unroll
  for (int mi = 0; mi < 8; ++mi) {
#pragma unroll
    for (int rr = 0; rr < 4; ++rr) {
      int grow = mt * BM + wm + mi * 16 + ls * 4 + rr;
      if (grow < n_e) {
        h16* yrow = y16 + (size_t)(base + grow) * H + (size_t)nt * 256 + wn;
#pragma unroll
        for (int nj = 0; nj < 4; ++nj)
          yrow[nj * 16 + lr] = (h16)acc[mi][nj][rr];
      }
    }
  }
}

extern "C" void kernel_launch(void* const* d_in, const int* in_sizes, int n_in,
                              void* d_out, int out_size, void* d_ws, size_t ws_size,
                              hipStream_t stream) {
  const float* x  = (const float*)d_in[0];
  const float* rl = (const float*)d_in[1];
  const float* w1 = (const float*)d_in[2];
  const float* w3 = (const float*)d_in[3];
  const float* w2 = (const float*)d_in[4];
  float* out = (float*)d_out;

  char* ws = (char*)d_ws;
  size_t off = 0;
  auto alloc = [&](size_t bytes) -> void* {
    void* p = ws + off;
    off = (off + bytes + 255) & ~(size_t)255;
    return p;
  };
  h16*   x16  = (h16*)  alloc((size_t)T * H * sizeof(h16));
  h16*   act  = (h16*)  alloc((size_t)(NENT + SLACK) * F * sizeof(h16));
  int*   etok = (int*)  alloc((size_t)(NENT + SLACK) * sizeof(int));
  float* ew   = (float*)alloc((size_t)(NENT + SLACK) * sizeof(float));
  int*   topi = (int*)  alloc((size_t)NENT * sizeof(int));
  float* topw = (float*)alloc((size_t)NENT * sizeof(float));
  int* tok2ent = (int*) alloc((size_t)NENT * sizeof(int));
  int* counts = (int*)  alloc(64);
  int* offs   = (int*)  alloc(64);
  int* fill   = (int*)  alloc(64);
  h16* w1h = (h16*)alloc((size_t)E * F * H * sizeof(h16));
  h16* w3h = (h16*)alloc((size_t)E * F * H * sizeof(h16));
  h16* w2h = (h16*)alloc((size_t)E * H * F * sizeof(h16));
  h16* y16 = (h16*)alloc((size_t)(NENT + SLACK) * H * sizeof(h16));
  (void)in_sizes; (void)n_in; (void)ws_size;

  k_init_counts<<<1, 64, 0, stream>>>(counts);
  k_routing<<<(T + 255) / 256, 256, 0, stream>>>(rl, topi, topw, counts);
  k_prefix<<<1, 64, 0, stream>>>(counts, offs, fill);
  k_scatter<<<(T + 255) / 256, 256, 0, stream>>>(topi, topw, offs, fill, etok, ew, tok2ent);
  k_cvt<<<(T * H / 8) / 256, 256, 0, stream>>>(x, x16);
  constexpr int WG = (E * F * H / 8) / 256;  // 11264
  k_cvt<<<WG, 256, 0, stream>>>(w1, w1h);
  k_cvt<<<WG, 256, 0, stream>>>(w3, w3h);
  k_cvt<<<WG, 256, 0, stream>>>(w2, w2h);
  k_gemm1<<<E * MT256 * NT1b, 512, 0, stream>>>(x16, w1h, w3h, counts, offs, etok, act);
  k_gemm2<<<E * MT256 * NT2b, 512, 0, stream>>>(act, w2h, counts, offs, y16);
  k_combine<<<(T * H / 8) / 256, 256, 0, stream>>>(y16, tok2ent, topw, out);
}

// Round 6
// 650.889 us; speedup vs baseline: 1.1681x; 1.1681x over previous
//
#include <hip/hip_runtime.h>
#include <hip/hip_bf16.h>

typedef _Float16 h16;
typedef _Float16 f16x8 __attribute__((ext_vector_type(8)));
typedef float f32x4 __attribute__((ext_vector_type(4)));

constexpr int T = 8192, H = 1024, F = 2816, E = 8;
constexpr int NENT = T * 2;
constexpr int SLACK = 128;
constexpr int BM = 256, BK = 64;
constexpr int MT256 = T / BM;       // 32
constexpr int NT1b = F / 128;       // 22  (gemm1 BN=128, x2 matrices)
constexpr int NT2b = H / 256;       // 4   (gemm2 BN=256)
constexpr int NKH = H / BK;         // 16
constexpr int NKF = F / BK;         // 44

#define GLD16(gptr, lptr)                                                        \
  __builtin_amdgcn_global_load_lds(                                              \
      (const __attribute__((address_space(1))) unsigned int*)(gptr),             \
      (__attribute__((address_space(3))) unsigned int*)(lptr), 16, 0, 0)

#define ASM_VMCNT(n) asm volatile("s_waitcnt vmcnt(" #n ")" ::: "memory")
#define SBAR()       __builtin_amdgcn_s_barrier()

// Per-half LDS tile: logical rows x 32 h16 packed as phys [rows/2][64 h16]
// (128 B/phys-row), XOR-swizzled 16B slots. Conflict-free (verified R2-R5).
__device__ __forceinline__ int lds_off(int row, int s) {
  int r2 = row >> 1;
  int p = (((row & 1) << 2) | s) ^ (r2 & 7);
  return r2 * 128 + p * 16;
}
// global_load_lds writes chunk c (1 KB) linearly: lane i -> phys r2=c*8+(i>>3),
// phys slot i&7. Logical (row,col within 32-k half) that belongs there:
__device__ __forceinline__ void inv_rowcol(int c, int i, int& row, int& col) {
  int r2 = c * 8 + (i >> 3);
  int slot8 = (i & 7) ^ (r2 & 7);
  row = r2 * 2 + (slot8 >> 2);
  col = (slot8 & 3) * 8;
}

// ---------------- routing ----------------
__global__ void k_routing(const float* __restrict__ logits,
                          int* __restrict__ top_i, float* __restrict__ top_w,
                          int* __restrict__ counts) {
  int t = blockIdx.x * blockDim.x + threadIdx.x;
  if (t >= T) return;
  float l[E];
#pragma unroll
  for (int j = 0; j < E; ++j) l[j] = logits[t * E + j];
  int i1 = 0; float v1 = l[0];
#pragma unroll
  for (int j = 1; j < E; ++j) if (l[j] > v1) { v1 = l[j]; i1 = j; }
  int i2 = -1; float v2 = -3.4e38f;
#pragma unroll
  for (int j = 0; j < E; ++j) if (j != i1 && l[j] > v2) { v2 = l[j]; i2 = j; }
  float e2 = __expf(v2 - v1);
  float inv = 1.0f / (1.0f + e2);
  top_i[2 * t] = i1; top_i[2 * t + 1] = i2;
  top_w[2 * t] = inv; top_w[2 * t + 1] = e2 * inv;
  atomicAdd(&counts[i1], 1);
  atomicAdd(&counts[i2], 1);
}

__global__ void k_init_counts(int* counts) {
  if (threadIdx.x < E) counts[threadIdx.x] = 0;
}

__global__ void k_prefix(const int* __restrict__ counts, int* __restrict__ offs,
                         int* __restrict__ fill) {
  if (threadIdx.x == 0) {
    int s = 0;
    for (int e = 0; e < E; ++e) { offs[e] = s; s += counts[e]; fill[e] = 0; }
  }
}

__global__ void k_scatter(const int* __restrict__ top_i, const float* __restrict__ top_w,
                          const int* __restrict__ offs, int* __restrict__ fill,
                          int* __restrict__ etok, float* __restrict__ ew,
                          int* __restrict__ tok2ent) {
  int t = blockIdx.x * blockDim.x + threadIdx.x;
  if (t >= T) return;
#pragma unroll
  for (int k = 0; k < 2; ++k) {
    int e = top_i[2 * t + k];
    int pos = atomicAdd(&fill[e], 1);
    int idx = offs[e] + pos;
    etok[idx] = t;
    ew[idx] = top_w[2 * t + k];
    tok2ent[2 * t + k] = idx;
  }
}

// ---------------- fp32 -> fp16 ----------------
__global__ void k_cvt(const float* __restrict__ s, h16* __restrict__ d) {
  size_t i = (size_t)(blockIdx.x * blockDim.x + threadIdx.x) * 8;
  float4 a = *(const float4*)(s + i);
  float4 b = *(const float4*)(s + i + 4);
  f16x8 h = {(h16)a.x, (h16)a.y, (h16)a.z, (h16)a.w,
             (h16)b.x, (h16)b.y, (h16)b.z, (h16)b.w};
  *(f16x8*)(d + i) = h;
}

// ---------------- combine: out[t] = w0*y[p0] + w1*y[p1] ----------------
__global__ void k_combine(const h16* __restrict__ y, const int* __restrict__ tok2ent,
                          const float* __restrict__ topw, float* __restrict__ out) {
  int i = blockIdx.x * blockDim.x + threadIdx.x;
  int t = i >> 7;
  int h0 = (i & 127) << 3;
  int p0 = tok2ent[2 * t], p1 = tok2ent[2 * t + 1];
  float w0 = topw[2 * t], w1 = topw[2 * t + 1];
  f16x8 y0 = *(const f16x8*)(y + (size_t)p0 * H + h0);
  f16x8 y1 = *(const f16x8*)(y + (size_t)p1 * H + h0);
  float4 o0, o1;
  o0.x = w0 * (float)y0[0] + w1 * (float)y1[0];
  o0.y = w0 * (float)y0[1] + w1 * (float)y1[1];
  o0.z = w0 * (float)y0[2] + w1 * (float)y1[2];
  o0.w = w0 * (float)y0[3] + w1 * (float)y1[3];
  o1.x = w0 * (float)y0[4] + w1 * (float)y1[4];
  o1.y = w0 * (float)y0[5] + w1 * (float)y1[5];
  o1.z = w0 * (float)y0[6] + w1 * (float)y1[6];
  o1.w = w0 * (float)y0[7] + w1 * (float)y1[7];
  *(float4*)(out + (size_t)t * H + h0) = o0;
  *(float4*)(out + (size_t)t * H + h0 + 4) = o1;
}

// ---------------- GEMM1: 256x(128x2), m201-style 4-phase/K-tile ----------------
// LDS per dbuf (64KB): A-kh0 16K | A-kh1 16K | B1-kh0 8K | B1-kh1 8K | B3-kh0 8K | B3-kh1 8K
__launch_bounds__(512, 2)
__global__ void k_gemm1(const h16* __restrict__ x16,
                        const h16* __restrict__ w1h, const h16* __restrict__ w3h,
                        const int* __restrict__ counts, const int* __restrict__ offs,
                        const int* __restrict__ etok, h16* __restrict__ act) {
  constexpr int NWG = E * MT256 * NT1b;              // 5632, %8==0
  int orig = blockIdx.x;
  int bid = (orig & 7) * (NWG / 8) + (orig >> 3);
  int e  = bid / (MT256 * NT1b);
  int r  = bid % (MT256 * NT1b);
  int nt = r / MT256;
  int mt = r % MT256;
  int n_e = counts[e];
  if (mt * BM >= n_e) return;
  int base = offs[e];

  __shared__ char lds[131072];

  int tid = threadIdx.x;
  int lane = tid & 63, wid = tid >> 6;
  int wm = (wid >> 2) * 128;
  int wn = (wid & 3) * 32;
  int lr = lane & 15, ls = lane >> 4;

  // region bases
  auto Ab  = [&](int d, int h) -> char* { return lds + d * 65536 + h * 16384; };
  auto B1b = [&](int d, int h) -> char* { return lds + d * 65536 + 32768 + h * 8192; };
  auto B3b = [&](int d, int h) -> char* { return lds + d * 65536 + 49152 + h * 8192; };

  // staging sources (k added at issue: ktile*64 + h*32)
  const h16* gA[2];
#pragma unroll
  for (int j = 0; j < 2; ++j) {
    int row, col;
    inv_rowcol(2 * wid + j, lane, row, col);
    int gr = mt * BM + row; if (gr >= n_e) gr = n_e - 1;
    gA[j] = x16 + (size_t)etok[base + gr] * H + col;
  }
  const h16 *gB1, *gB3;
  {
    int row, col;
    inv_rowcol(wid, lane, row, col);
    size_t w = ((size_t)e * F + (size_t)nt * 128 + row) * H + col;
    gB1 = w1h + w;
    gB3 = w3h + w;
  }

  auto stA = [&](int d, int h, int kt) {
#pragma unroll
    for (int j = 0; j < 2; ++j)
      GLD16(gA[j] + kt * 64 + h * 32, Ab(d, h) + (2 * wid + j) * 1024);
  };
  auto stB = [&](int d, int h, int kt) {
    GLD16(gB1 + kt * 64 + h * 32, B1b(d, h) + wid * 1024);
    GLD16(gB3 + kt * 64 + h * 32, B3b(d, h) + wid * 1024);
  };

  int aoff[8], boff[2];
#pragma unroll
  for (int mi = 0; mi < 8; ++mi) aoff[mi] = lds_off(wm + mi * 16 + lr, ls);
#pragma unroll
  for (int nj = 0; nj < 2; ++nj) boff[nj] = lds_off(wn + nj * 16 + lr, ls);

  f32x4 ag[8][2] = {{{0.f,0.f,0.f,0.f}}};
  f32x4 au[8][2] = {{{0.f,0.f,0.f,0.f}}};

#define G1_MFMA(MI0, AF, B1F, B3F)                                               \
  __builtin_amdgcn_s_setprio(1);                                                 \
  _Pragma("unroll") for (int m = 0; m < 4; ++m)                                  \
  _Pragma("unroll") for (int nj = 0; nj < 2; ++nj) {                             \
    ag[MI0 + m][nj] = __builtin_amdgcn_mfma_f32_16x16x32_f16(AF[m], B1F[nj], ag[MI0 + m][nj], 0, 0, 0); \
    au[MI0 + m][nj] = __builtin_amdgcn_mfma_f32_16x16x32_f16(AF[m], B3F[nj], au[MI0 + m][nj], 0, 0, 0); \
  }                                                                              \
  __builtin_amdgcn_s_setprio(0);

  // prologue: tile0 fully (8), tile1 all but A-kh1 (6)
  stA(0, 0, 0); stB(0, 0, 0); stB(0, 1, 0); stA(0, 1, 0);
  stB(1, 0, 1); stB(1, 1, 1); stA(1, 0, 1);
  ASM_VMCNT(6);
  SBAR();

  for (int t = 0; t < NKH; ++t) {
    int cur = t & 1;
    // ---- ph0: A[0-3]kh0 + B kh0 reads; stage A-kh1(t+1) -> dbuf cur^1 ----
    f16x8 aL0[4], b1k0[2], b3k0[2];
#pragma unroll
    for (int m = 0; m < 4; ++m) aL0[m] = *(const f16x8*)(Ab(cur, 0) + aoff[m]);
#pragma unroll
    for (int nj = 0; nj < 2; ++nj) {
      b1k0[nj] = *(const f16x8*)(B1b(cur, 0) + boff[nj]);
      b3k0[nj] = *(const f16x8*)(B3b(cur, 0) + boff[nj]);
    }
    if (t + 1 < NKH) stA(cur ^ 1, 1, t + 1);
    SBAR();
    G1_MFMA(0, aL0, b1k0, b3k0)
    SBAR();
    // ---- ph1: A[0-3]kh1 + B kh1 reads; stage B-kh0(t+2) -> cur ----
    f16x8 aL1[4], b1k1[2], b3k1[2];
#pragma unroll
    for (int m = 0; m < 4; ++m) aL1[m] = *(const f16x8*)(Ab(cur, 1) + aoff[m]);
#pragma unroll
    for (int nj = 0; nj < 2; ++nj) {
      b1k1[nj] = *(const f16x8*)(B1b(cur, 1) + boff[nj]);
      b3k1[nj] = *(const f16x8*)(B3b(cur, 1) + boff[nj]);
    }
    if (t + 2 < NKH) stB(cur, 0, t + 2);
    SBAR();
    G1_MFMA(0, aL1, b1k1, b3k1)
    SBAR();
    // ---- ph2: A[4-7]kh0 reads; stage B-kh1(t+2) -> cur ----
    f16x8 aH0[4];
#pragma unroll
    for (int m = 0; m < 4; ++m) aH0[m] = *(const f16x8*)(Ab(cur, 0) + aoff[4 + m]);
    if (t + 2 < NKH) stB(cur, 1, t + 2);
    SBAR();
    G1_MFMA(4, aH0, b1k0, b3k0)
    SBAR();
    // ---- ph3: A[4-7]kh1 reads; stage A-kh0(t+2) -> cur; vmcnt; bar ----
    f16x8 aH1[4];
#pragma unroll
    for (int m = 0; m < 4; ++m) aH1[m] = *(const f16x8*)(Ab(cur, 1) + aoff[4 + m]);
    if (t + 2 < NKH) stA(cur, 0, t + 2);
    SBAR();
    G1_MFMA(4, aH1, b1k1, b3k1)
    if (t + 2 < NKH) { ASM_VMCNT(6); } else { ASM_VMCNT(0); }
    SBAR();
  }
#undef G1_MFMA

  // epilogue: silu(g)*u -> act fp16
#pragma unroll
  for (int mi = 0; mi < 8; ++mi) {
#pragma unroll
    for (int rr = 0; rr < 4; ++rr) {
      int grow = mt * BM + wm + mi * 16 + ls * 4 + rr;
      if (grow < n_e) {
        size_t rowb = (size_t)(base + grow) * F + (size_t)nt * 128 + wn;
#pragma unroll
        for (int nj = 0; nj < 2; ++nj) {
          float g = ag[mi][nj][rr];
          float u = au[mi][nj][rr];
          float s = g / (1.0f + __expf(-g)) * u;
          act[rowb + nj * 16 + lr] = (h16)s;
        }
      }
    }
  }
}

// ---------------- GEMM2: 256x256, m201-style 4-phase/K-tile ----------------
// LDS per dbuf (64KB): A-kh0 16K | A-kh1 16K | B-kh0 16K | B-kh1 16K
__launch_bounds__(512, 2)
__global__ void k_gemm2(const h16* __restrict__ act, const h16* __restrict__ w2h,
                        const int* __restrict__ counts, const int* __restrict__ offs,
                        h16* __restrict__ y16) {
  constexpr int NWG = E * MT256 * NT2b;              // 1024, %8==0
  int orig = blockIdx.x;
  int bid = (orig & 7) * (NWG / 8) + (orig >> 3);
  int e  = bid / (MT256 * NT2b);
  int r  = bid % (MT256 * NT2b);
  int nt = r / MT256;
  int mt = r % MT256;
  int n_e = counts[e];
  if (mt * BM >= n_e) return;
  int base = offs[e];

  __shared__ char lds[131072];

  int tid = threadIdx.x;
  int lane = tid & 63, wid = tid >> 6;
  int wm = (wid >> 2) * 128;
  int wn = (wid & 3) * 64;
  int lr = lane & 15, ls = lane >> 4;

  auto Ab = [&](int d, int h) -> char* { return lds + d * 65536 + h * 16384; };
  auto Bb = [&](int d, int h) -> char* { return lds + d * 65536 + 32768 + h * 16384; };

  const h16* gA[2]; const h16* gB[2];
#pragma unroll
  for (int j = 0; j < 2; ++j) {
    int row, col;
    inv_rowcol(2 * wid + j, lane, row, col);
    int gr = mt * BM + row; if (gr >= n_e) gr = n_e - 1;
    gA[j] = act + (size_t)(base + gr) * F + col;
    gB[j] = w2h + ((size_t)e * H + (size_t)nt * 256 + row) * F + col;
  }

  auto stA = [&](int d, int h, int kt) {
#pragma unroll
    for (int j = 0; j < 2; ++j)
      GLD16(gA[j] + kt * 64 + h * 32, Ab(d, h) + (2 * wid + j) * 1024);
  };
  auto stB = [&](int d, int h, int kt) {
#pragma unroll
    for (int j = 0; j < 2; ++j)
      GLD16(gB[j] + kt * 64 + h * 32, Bb(d, h) + (2 * wid + j) * 1024);
  };

  int aoff[8], boff[4];
#pragma unroll
  for (int mi = 0; mi < 8; ++mi) aoff[mi] = lds_off(wm + mi * 16 + lr, ls);
#pragma unroll
  for (int nj = 0; nj < 4; ++nj) boff[nj] = lds_off(wn + nj * 16 + lr, ls);

  f32x4 acc[8][4] = {{{0.f,0.f,0.f,0.f}}};

#define G2_MFMA(MI0, AF, BF)                                                     \
  __builtin_amdgcn_s_setprio(1);                                                 \
  _Pragma("unroll") for (int m = 0; m < 4; ++m)                                  \
  _Pragma("unroll") for (int nj = 0; nj < 4; ++nj) {                             \
    acc[MI0 + m][nj] = __builtin_amdgcn_mfma_f32_16x16x32_f16(AF[m], BF[nj], acc[MI0 + m][nj], 0, 0, 0); \
  }                                                                              \
  __builtin_amdgcn_s_setprio(0);

  stA(0, 0, 0); stB(0, 0, 0); stB(0, 1, 0); stA(0, 1, 0);
  stB(1, 0, 1); stB(1, 1, 1); stA(1, 0, 1);
  ASM_VMCNT(6);
  SBAR();

  for (int t = 0; t < NKF; ++t) {
    int cur = t & 1;
    // ph0
    f16x8 aL0[4], bk0[4];
#pragma unroll
    for (int m = 0; m < 4; ++m) aL0[m] = *(const f16x8*)(Ab(cur, 0) + aoff[m]);
#pragma unroll
    for (int nj = 0; nj < 4; ++nj) bk0[nj] = *(const f16x8*)(Bb(cur, 0) + boff[nj]);
    if (t + 1 < NKF) stA(cur ^ 1, 1, t + 1);
    SBAR();
    G2_MFMA(0, aL0, bk0)
    SBAR();
    // ph1
    f16x8 aL1[4], bk1[4];
#pragma unroll
    for (int m = 0; m < 4; ++m) aL1[m] = *(const f16x8*)(Ab(cur, 1) + aoff[m]);
#pragma unroll
    for (int nj = 0; nj < 4; ++nj) bk1[nj] = *(const f16x8*)(Bb(cur, 1) + boff[nj]);
    if (t + 2 < NKF) stB(cur, 0, t + 2);
    SBAR();
    G2_MFMA(0, aL1, bk1)
    SBAR();
    // ph2
    f16x8 aH0[4];
#pragma unroll
    for (int m = 0; m < 4; ++m) aH0[m] = *(const f16x8*)(Ab(cur, 0) + aoff[4 + m]);
    if (t + 2 < NKF) stB(cur, 1, t + 2);
    SBAR();
    G2_MFMA(4, aH0, bk0)
    SBAR();
    // ph3
    f16x8 aH1[4];
#pragma unroll
    for (int m = 0; m < 4; ++m) aH1[m] = *(const f16x8*)(Ab(cur, 1) + aoff[4 + m]);
    if (t + 2 < NKF) stA(cur, 0, t + 2);
    SBAR();
    G2_MFMA(4, aH1, bk1)
    if (t + 2 < NKF) { ASM_VMCNT(6); } else { ASM_VMCNT(0); }
    SBAR();
  }
#undef G2_MFMA

#pragma unroll
  for (int mi = 0; mi < 8; ++mi) {
#pragma unroll
    for (int rr = 0; rr < 4; ++rr) {
      int grow = mt * BM + wm + mi * 16 + ls * 4 + rr;
      if (grow < n_e) {
        h16* yrow = y16 + (size_t)(base + grow) * H + (size_t)nt * 256 + wn;
#pragma unroll
        for (int nj = 0; nj < 4; ++nj)
          yrow[nj * 16 + lr] = (h16)acc[mi][nj][rr];
      }
    }
  }
}

extern "C" void kernel_launch(void* const* d_in, const int* in_sizes, int n_in,
                              void* d_out, int out_size, void* d_ws, size_t ws_size,
                              hipStream_t stream) {
  const float* x  = (const float*)d_in[0];
  const float* rl = (const float*)d_in[1];
  const float* w1 = (const float*)d_in[2];
  const float* w3 = (const float*)d_in[3];
  const float* w2 = (const float*)d_in[4];
  float* out = (float*)d_out;

  char* ws = (char*)d_ws;
  size_t off = 0;
  auto alloc = [&](size_t bytes) -> void* {
    void* p = ws + off;
    off = (off + bytes + 255) & ~(size_t)255;
    return p;
  };
  h16*   x16  = (h16*)  alloc((size_t)T * H * sizeof(h16));
  h16*   act  = (h16*)  alloc((size_t)(NENT + SLACK) * F * sizeof(h16));
  int*   etok = (int*)  alloc((size_t)(NENT + SLACK) * sizeof(int));
  float* ew   = (float*)alloc((size_t)(NENT + SLACK) * sizeof(float));
  int*   topi = (int*)  alloc((size_t)NENT * sizeof(int));
  float* topw = (float*)alloc((size_t)NENT * sizeof(float));
  int* tok2ent = (int*) alloc((size_t)NENT * sizeof(int));
  int* counts = (int*)  alloc(64);
  int* offs   = (int*)  alloc(64);
  int* fill   = (int*)  alloc(64);
  h16* w1h = (h16*)alloc((size_t)E * F * H * sizeof(h16));
  h16* w3h = (h16*)alloc((size_t)E * F * H * sizeof(h16));
  h16* w2h = (h16*)alloc((size_t)E * H * F * sizeof(h16));
  h16* y16 = (h16*)alloc((size_t)(NENT + SLACK) * H * sizeof(h16));
  (void)in_sizes; (void)n_in; (void)ws_size;

  k_init_counts<<<1, 64, 0, stream>>>(counts);
  k_routing<<<(T + 255) / 256, 256, 0, stream>>>(rl, topi, topw, counts);
  k_prefix<<<1, 64, 0, stream>>>(counts, offs, fill);
  k_scatter<<<(T + 255) / 256, 256, 0, stream>>>(topi, topw, offs, fill, etok, ew, tok2ent);
  k_cvt<<<(T * H / 8) / 256, 256, 0, stream>>>(x, x16);
  constexpr int WG = (E * F * H / 8) / 256;  // 11264
  k_cvt<<<WG, 256, 0, stream>>>(w1, w1h);
  k_cvt<<<WG, 256, 0, stream>>>(w3, w3h);
  k_cvt<<<WG, 256, 0, stream>>>(w2, w2h);
  k_gemm1<<<E * MT256 * NT1b, 512, 0, stream>>>(x16, w1h, w3h, counts, offs, etok, act);
  k_gemm2<<<E * MT256 * NT2b, 512, 0, stream>>>(act, w2h, counts, offs, y16);
  k_combine<<<(T * H / 8) / 256, 256, 0, stream>>>(y16, tok2ent, topw, out);
}